// Round 6
// baseline (25.931 us; speedup 1.0000x reference)
//
#include <hip/hip_runtime.h>

#define H 512
#define W 512
#define C 3
#define HW (H * W)

typedef float f32x4 __attribute__((ext_vector_type(4)));

// 4x8 output tile per thread (4 wide, 8 tall). Block (64,4): each block covers
// a 256-px x segment and 32 y rows. 1D grid of 1024 blocks, XCD-chunked
// swizzle: each of the 8 XCDs owns 4 complete images (128 consecutive
// blocks), keeping halo/streaming reuse inside one XCD's 4 MB L2.
// 10 loaded rows per 8 output rows = 1.25x vertical read amplification
// (was 1.5x with the 4-row tile), 30 float4 loads per 32 outputs.
__global__ __launch_bounds__(256) void sobel_kernel(const float* __restrict__ img,
                                                    float* __restrict__ out) {
    // --- XCD-chunked swizzle: nwg = 1024 = 8 XCDs x 128 ---
    const int bid = blockIdx.x;
    const int swz = (bid & 7) * 128 + (bid >> 3);    // xcd*chunk + idx
    const int bz  = swz >> 5;                        // image index (32 blocks/img)
    const int rem = swz & 31;
    const int by  = rem >> 1;                        // 16 y-bands of 32 rows
    const int bx  = rem & 1;                         // 2 x-halves

    const int tx = threadIdx.x;                      // 0..63 (lane)
    const int ty = threadIdx.y;                      // 0..3  (wave)
    const int x0 = bx * 256 + tx * 4;                // multiple of 4
    const int y0 = (by * 4 + ty) * 8;                // multiple of 8
    const int n  = bz;

    const float* p0 = img + (size_t)n * C * HW;
    const float* p1 = p0 + HW;
    const float* p2 = p0 + 2 * HW;

    // Row offsets (edge-pad == clamp loaded rows into [0, H-1]).
    size_t ro[10];
#pragma unroll
    for (int j = 0; j < 10; ++j) {
        int row = y0 - 1 + j;
        row = min(max(row, 0), H - 1);
        ro[j] = (size_t)row * W;
    }

    // ---- prologue: issue ALL vector loads back-to-back ----
    f32x4 A[10][3];
#pragma unroll
    for (int j = 0; j < 10; ++j) {
        A[j][0] = *reinterpret_cast<const f32x4*>(p0 + ro[j] + x0);
        A[j][1] = *reinterpret_cast<const f32x4*>(p1 + ro[j] + x0);
        A[j][2] = *reinterpret_cast<const f32x4*>(p2 + ro[j] + x0);
    }

    // Block-boundary halo column (only lanes 0 and 63 load).
    const int  ecol  = (tx == 0) ? (x0 - 1) : (x0 + 4);
    const bool eneed = (tx == 0 && x0 > 0) || (tx == 63 && x0 + 4 < W);
    float e[10];
#pragma unroll
    for (int j = 0; j < 10; ++j) e[j] = 0.f;
    if (eneed) {
#pragma unroll
        for (int j = 0; j < 10; ++j)
            e[j] = p0[ro[j] + ecol] + p1[ro[j] + ecol] + p2[ro[j] + ecol];
    }

    float gx[8][4];
    float gy[8][4];

#pragma unroll
    for (int j = 0; j < 10; ++j) {
        const float s0 = A[j][0].x + A[j][1].x + A[j][2].x;
        const float s1 = A[j][0].y + A[j][1].y + A[j][2].y;
        const float s2 = A[j][0].z + A[j][1].z + A[j][2].z;
        const float s3 = A[j][0].w + A[j][1].w + A[j][2].w;

        float left = __shfl_up(s3, 1);
        if (tx == 0) left = e[j];          // garbage when x0==0; result discarded
        float right = __shfl_down(s0, 1);
        if (tx == 63) right = e[j];        // garbage when x0+4==W; result discarded

        const float win[6] = {left, s0, s1, s2, s3, right};

        float cd[4], cs[4];
#pragma unroll
        for (int m = 0; m < 4; ++m) {
            cd[m] = win[m] - win[m + 2];                       // Gx col weights [1,0,-1]
            cs[m] = win[m] + 2.f * win[m + 1] + win[m + 2];    // Gy col weights [1,2,1]
        }

        // Output row k (center y0+k) uses loaded rows k, k+1, k+2:
        //   gx[k] = cd[k] + 2*cd[k+1] + cd[k+2];  gy[k] = cs[k] - cs[k+2]
#pragma unroll
        for (int m = 0; m < 4; ++m) {
            if (j < 8)             { gx[j][m] = cd[m];       gy[j][m] = cs[m]; }
            if (j >= 1 && j <= 8)  { gx[j - 1][m] += 2.f * cd[m]; }
            if (j >= 2)            { gx[j - 2][m] += cd[m];  gy[j - 2][m] -= cs[m]; }
        }
    }

    float res[8][4];
#pragma unroll
    for (int k = 0; k < 8; ++k)
#pragma unroll
        for (int m = 0; m < 4; ++m) {
            // Tolerance is 0.75; single v_sqrt_f32 (~1 ulp) is plenty.
            res[k][m] = __builtin_amdgcn_sqrtf(gx[k][m] * gx[k][m] + gy[k][m] * gy[k][m]);
        }

    // Edge-pad fixups (result duplication). x first, then y (y copies fixed rows).
    if (x0 == 0) {
#pragma unroll
        for (int k = 0; k < 8; ++k) res[k][0] = res[k][1];
    }
    if (x0 == W - 4) {
#pragma unroll
        for (int k = 0; k < 8; ++k) res[k][3] = res[k][2];
    }
    if (y0 == 0) {
#pragma unroll
        for (int m = 0; m < 4; ++m) res[0][m] = res[1][m];
    }
    if (y0 == H - 8) {
#pragma unroll
        for (int m = 0; m < 4; ++m) res[7][m] = res[6][m];
    }

    // Streaming (non-temporal) stores: output is never re-read; keep L2 for img.
    float* o = out + (size_t)n * HW + (size_t)y0 * W + x0;
#pragma unroll
    for (int k = 0; k < 8; ++k) {
        f32x4 v = {res[k][0], res[k][1], res[k][2], res[k][3]};
        __builtin_nontemporal_store(v, reinterpret_cast<f32x4*>(o + (size_t)k * W));
    }
}

extern "C" void kernel_launch(void* const* d_in, const int* in_sizes, int n_in,
                              void* d_out, int out_size, void* d_ws, size_t ws_size,
                              hipStream_t stream) {
    const float* img = (const float*)d_in[0];
    float* out = (float*)d_out;

    dim3 block(64, 4, 1);
    dim3 grid(1024, 1, 1);   // 8 XCDs x 128-block chunks (see swizzle)
    sobel_kernel<<<grid, block, 0, stream>>>(img, out);
}

// Round 7
// 25.240 us; speedup vs baseline: 1.0274x; 1.0274x over previous
//
#include <hip/hip_runtime.h>

#define H 512
#define W 512
#define C 3
#define HW (H * W)

typedef float f32x4 __attribute__((ext_vector_type(4)));

// 4x4 output tile per thread. Block (64,4): each block covers a 256-px x
// segment and 16 y rows. 1D grid of 2048 blocks, XCD-chunked swizzle:
// each of the 8 XCDs owns 4 complete images (256 consecutive blocks), so
// y-adjacent blocks (sharing halo rows / streaming neighbors) stay on the
// same XCD's 4 MB L2 instead of bouncing through L3.
// (Round-6 tried an 8-row tile: -17% vmem instructions, neutral-to-worse
//  time -> vmem issue rate is not the limiter; this is the best variant.)
__global__ __launch_bounds__(256) void sobel_kernel(const float* __restrict__ img,
                                                    float* __restrict__ out) {
    // --- XCD-chunked swizzle: nwg = 2048 = 8 XCDs x 256 ---
    const int bid = blockIdx.x;
    const int swz = (bid & 7) * 256 + (bid >> 3);    // xcd*chunk + idx
    const int bz  = swz >> 6;                        // image index (64 blocks/img)
    const int rem = swz & 63;
    const int by  = rem >> 1;                        // 32 y-bands
    const int bx  = rem & 1;                         // 2 x-halves

    const int tx = threadIdx.x;                      // 0..63 (lane)
    const int ty = threadIdx.y;                      // 0..3  (wave)
    const int x0 = bx * 256 + tx * 4;                // multiple of 4
    const int y0 = (by * 4 + ty) * 4;                // multiple of 4
    const int n  = bz;

    const float* p0 = img + (size_t)n * C * HW;
    const float* p1 = p0 + HW;
    const float* p2 = p0 + 2 * HW;

    // Row offsets (edge-pad == clamp center into [1,510] == clamp loaded rows).
    size_t ro[6];
#pragma unroll
    for (int j = 0; j < 6; ++j) {
        int row = y0 - 1 + j;
        row = min(max(row, 0), H - 1);
        ro[j] = (size_t)row * W;
    }

    // ---- prologue: issue ALL vector loads back-to-back ----
    f32x4 A[6][3];
#pragma unroll
    for (int j = 0; j < 6; ++j) {
        A[j][0] = *reinterpret_cast<const f32x4*>(p0 + ro[j] + x0);
        A[j][1] = *reinterpret_cast<const f32x4*>(p1 + ro[j] + x0);
        A[j][2] = *reinterpret_cast<const f32x4*>(p2 + ro[j] + x0);
    }

    // Block-boundary halo column (only lanes 0 and 63 load).
    const int  ecol  = (tx == 0) ? (x0 - 1) : (x0 + 4);
    const bool eneed = (tx == 0 && x0 > 0) || (tx == 63 && x0 + 4 < W);
    float e[6] = {0.f, 0.f, 0.f, 0.f, 0.f, 0.f};
    if (eneed) {
#pragma unroll
        for (int j = 0; j < 6; ++j)
            e[j] = p0[ro[j] + ecol] + p1[ro[j] + ecol] + p2[ro[j] + ecol];
    }

    float gx[4][4];
    float gy[4][4];

#pragma unroll
    for (int j = 0; j < 6; ++j) {
        const float s0 = A[j][0].x + A[j][1].x + A[j][2].x;
        const float s1 = A[j][0].y + A[j][1].y + A[j][2].y;
        const float s2 = A[j][0].z + A[j][1].z + A[j][2].z;
        const float s3 = A[j][0].w + A[j][1].w + A[j][2].w;

        float left = __shfl_up(s3, 1);
        if (tx == 0) left = e[j];          // garbage when x0==0; result discarded
        float right = __shfl_down(s0, 1);
        if (tx == 63) right = e[j];        // garbage when x0+4==W; result discarded

        const float win[6] = {left, s0, s1, s2, s3, right};

        float cd[4], cs[4];
#pragma unroll
        for (int m = 0; m < 4; ++m) {
            cd[m] = win[m] - win[m + 2];                       // Gx col weights [1,0,-1]
            cs[m] = win[m] + 2.f * win[m + 1] + win[m + 2];    // Gy col weights [1,2,1]
        }

        // Output row k (center row j=k+1) uses loaded rows k, k+1, k+2:
        //   gx[k] = cd[k] + 2*cd[k+1] + cd[k+2];  gy[k] = cs[k] - cs[k+2]
#pragma unroll
        for (int m = 0; m < 4; ++m) {
            if (j < 4)             { gx[j][m] = cd[m];       gy[j][m] = cs[m]; }
            if (j >= 1 && j <= 4)  { gx[j - 1][m] += 2.f * cd[m]; }
            if (j >= 2)            { gx[j - 2][m] += cd[m];  gy[j - 2][m] -= cs[m]; }
        }
    }

    float res[4][4];
#pragma unroll
    for (int k = 0; k < 4; ++k)
#pragma unroll
        for (int m = 0; m < 4; ++m) {
            // Tolerance is 0.75; single v_sqrt_f32 (~1 ulp) is plenty.
            res[k][m] = __builtin_amdgcn_sqrtf(gx[k][m] * gx[k][m] + gy[k][m] * gy[k][m]);
        }

    // Edge-pad fixups (result duplication). x first, then y (y copies fixed rows).
    if (x0 == 0) {
#pragma unroll
        for (int k = 0; k < 4; ++k) res[k][0] = res[k][1];
    }
    if (x0 == W - 4) {
#pragma unroll
        for (int k = 0; k < 4; ++k) res[k][3] = res[k][2];
    }
    if (y0 == 0) {
#pragma unroll
        for (int m = 0; m < 4; ++m) res[0][m] = res[1][m];
    }
    if (y0 == H - 4) {
#pragma unroll
        for (int m = 0; m < 4; ++m) res[3][m] = res[2][m];
    }

    // Streaming (non-temporal) stores: output is never re-read; keep L2 for img.
    float* o = out + (size_t)n * HW + (size_t)y0 * W + x0;
#pragma unroll
    for (int k = 0; k < 4; ++k) {
        f32x4 v = {res[k][0], res[k][1], res[k][2], res[k][3]};
        __builtin_nontemporal_store(v, reinterpret_cast<f32x4*>(o + (size_t)k * W));
    }
}

extern "C" void kernel_launch(void* const* d_in, const int* in_sizes, int n_in,
                              void* d_out, int out_size, void* d_ws, size_t ws_size,
                              hipStream_t stream) {
    const float* img = (const float*)d_in[0];
    float* out = (float*)d_out;

    dim3 block(64, 4, 1);
    dim3 grid(2048, 1, 1);   // 8 XCDs x 256-block chunks (see swizzle)
    sobel_kernel<<<grid, block, 0, stream>>>(img, out);
}